// Round 1
// baseline (1332.990 us; speedup 1.0000x reference)
//
#include <hip/hip_runtime.h>

#define HH 100
#define G4 400      // 4*H
#define TT 256
#define BB 16
#define TB 4096     // T*B
#define VV 30522
#define GX_ROWS 8
#define PR 64       // tb rows per projection block

// ---- transpose W_ih [400,100] -> [100,400] ----
__global__ void k_tw_ih(const float* __restrict__ W, float* __restrict__ Wt) {
    int idx = blockIdx.x * blockDim.x + threadIdx.x;
    if (idx < G4 * HH) {
        int j = idx / HH, k = idx - j * HH;
        Wt[k * G4 + j] = W[idx];
    }
}

// ---- transpose out_W [V,100] -> [100,V] ----
__global__ void k_tw_out(const float* __restrict__ W, float* __restrict__ Wt) {
    int v = blockIdx.x * blockDim.x + threadIdx.x;
    if (v < VV) {
        #pragma unroll 4
        for (int k = 0; k < HH; ++k) Wt[(long)k * VV + v] = W[(long)v * HH + k];
    }
}

// ---- gx[t,b,:] = emb[tok[t,b]] @ W_ih^T + b_ih + b_hh ----
__global__ __launch_bounds__(256) void k_gx(const int* __restrict__ tok,
                                            const float* __restrict__ emb,
                                            const float* __restrict__ WtIh,
                                            const float* __restrict__ bih,
                                            const float* __restrict__ bhh,
                                            float* __restrict__ gx) {
    __shared__ float x_s[GX_ROWS * HH];
    int tid = threadIdx.x;
    int row0 = blockIdx.x * GX_ROWS;
    for (int i = tid; i < GX_ROWS * HH; i += 256) {
        int r = i / HH, k = i - r * HH;
        x_s[i] = emb[(long)tok[row0 + r] * HH + k];
    }
    __syncthreads();
    for (int j = tid; j < G4; j += 256) {
        float bias = bih[j] + bhh[j];
        float acc[GX_ROWS];
        #pragma unroll
        for (int r = 0; r < GX_ROWS; ++r) acc[r] = bias;
        for (int k = 0; k < HH; ++k) {
            float w = WtIh[k * G4 + j];
            #pragma unroll
            for (int r = 0; r < GX_ROWS; ++r) acc[r] += w * x_s[r * HH + k];
        }
        #pragma unroll
        for (int r = 0; r < GX_ROWS; ++r) gx[(long)(row0 + r) * G4 + j] = acc[r];
    }
}

// ---- sequential decoder LSTM: one block per batch element ----
__global__ __launch_bounds__(512) void k_lstm(const float* __restrict__ gx,
                                              const float* __restrict__ Whh,
                                              float* __restrict__ dec) {
    __shared__ float h_s[HH];
    __shared__ float gates_s[G4];
    int tid = threadIdx.x;
    int b = blockIdx.x;
    float w[HH];
    if (tid < G4) {
        #pragma unroll
        for (int k = 0; k < HH; ++k) w[k] = Whh[tid * HH + k];
    }
    float c = 0.f;
    if (tid < HH) h_s[tid] = 0.f;
    __syncthreads();
    for (int t = 0; t < TT; ++t) {
        int row = t * BB + b;
        if (tid < G4) {
            float gxv = gx[(long)row * G4 + tid];
            float a0 = 0.f, a1 = 0.f, a2 = 0.f, a3 = 0.f;
            #pragma unroll
            for (int k = 0; k < HH; k += 4) {
                a0 += w[k]     * h_s[k];
                a1 += w[k + 1] * h_s[k + 1];
                a2 += w[k + 2] * h_s[k + 2];
                a3 += w[k + 3] * h_s[k + 3];
            }
            gates_s[tid] = gxv + ((a0 + a1) + (a2 + a3));
        }
        __syncthreads();
        if (tid < HH) {
            float gi = gates_s[tid];
            float gf = gates_s[HH + tid];
            float gg = gates_s[2 * HH + tid];
            float go = gates_s[3 * HH + tid];
            float si = 1.f / (1.f + expf(-gi));
            float sf = 1.f / (1.f + expf(-gf));
            float so = 1.f / (1.f + expf(-go));
            float tg = tanhf(gg);
            c = sf * c + si * tg;
            float h = so * tanhf(c);
            h_s[tid] = h;
            dec[(long)row * HH + tid] = h;
        }
        __syncthreads();
    }
}

// ---- projection: out[tb, v] = dec[tb,:] . out_W[v,:] + out_b[v] ----
__global__ __launch_bounds__(256) void k_proj(const float* __restrict__ dec,
                                              const float* __restrict__ Wt,
                                              const float* __restrict__ ob,
                                              float* __restrict__ out) {
    __shared__ float dec_t[HH * PR];   // [k][r], 25.6 KB
    int tid = threadIdx.x;
    int r0 = blockIdx.y * PR;
    // load + transpose dec tile (global read is one contiguous flat range)
    for (int i = tid; i < PR * HH; i += 256) {
        int r = i / HH, k = i - r * HH;
        dec_t[k * PR + r] = dec[(long)r0 * HH + i];
    }
    __syncthreads();
    int v = blockIdx.x * 256 + tid;
    bool ok = v < VV;
    float acc[PR];
    #pragma unroll
    for (int r = 0; r < PR; ++r) acc[r] = 0.f;
    float wv = ok ? Wt[v] : 0.f;   // k = 0 weight
    for (int k = 0; k < HH; ++k) {
        float wn = (ok && k + 1 < HH) ? Wt[(long)(k + 1) * VV + v] : 0.f; // prefetch
        const float4* d4 = (const float4*)(&dec_t[k * PR]);
        #pragma unroll
        for (int q = 0; q < PR / 4; ++q) {
            float4 d = d4[q];
            acc[4 * q + 0] += d.x * wv;
            acc[4 * q + 1] += d.y * wv;
            acc[4 * q + 2] += d.z * wv;
            acc[4 * q + 3] += d.w * wv;
        }
        wv = wn;
    }
    if (ok) {
        float bias = ob[v];
        #pragma unroll
        for (int r = 0; r < PR; ++r)
            out[(long)(r0 + r) * VV + v] = acc[r] + bias;
    }
}

extern "C" void kernel_launch(void* const* d_in, const int* in_sizes, int n_in,
                              void* d_out, int out_size, void* d_ws, size_t ws_size,
                              hipStream_t stream) {
    const int*   tok  = (const int*)d_in[0];
    const float* emb  = (const float*)d_in[1];
    // d_in[2..5] = encoder weights: outputs unused by the reference -> skipped
    const float* dWih = (const float*)d_in[6];
    const float* dWhh = (const float*)d_in[7];
    const float* dbih = (const float*)d_in[8];
    const float* dbhh = (const float*)d_in[9];
    const float* outW = (const float*)d_in[10];
    const float* outb = (const float*)d_in[11];
    float* out = (float*)d_out;

    float* ws    = (float*)d_ws;
    float* gx    = ws;                 // 4096*400
    float* dec   = gx + (long)TB * G4; // 4096*100
    float* WtIh  = dec + (long)TB * HH;   // 100*400
    float* WtOut = WtIh + (long)HH * G4;  // 100*30522  (total ~20.6 MB)

    k_tw_ih<<<(G4 * HH + 255) / 256, 256, 0, stream>>>(dWih, WtIh);
    k_tw_out<<<(VV + 255) / 256, 256, 0, stream>>>(outW, WtOut);
    k_gx<<<TB / GX_ROWS, 256, 0, stream>>>(tok, emb, WtIh, dbih, dbhh, gx);
    k_lstm<<<BB, 512, 0, stream>>>(gx, dWhh, dec);
    dim3 pg((VV + 255) / 256, TB / PR);
    k_proj<<<pg, 256, 0, stream>>>(dec, WtOut, outb, out);
}